// Round 2
// baseline (208.154 us; speedup 1.0000x reference)
//
#include <hip/hip_runtime.h>

#define Dm 128
#define Bn 16
#define TZ 8
#define TY 8
#define TX 16            // tile width in w; each thread owns a w-pair
#define HZ (TZ + 2)      // 10
#define HY (TY + 2)      // 10
#define HX (TX + 2)      // 18
#define TILE_N (HZ * HY * HX)  // 1800
#define NT 512
#define NLOAD ((TILE_N + NT - 1) / NT)  // 4
#define VOX (Dm * Dm * Dm)

__device__ __forceinline__ void gload_lds4(const void* g, void* l) {
  __builtin_amdgcn_global_load_lds(
      (const __attribute__((address_space(1))) void*)g,
      (__attribute__((address_space(3))) void*)l,
      4, 0, 0);
}

extern "C" __global__ void __launch_bounds__(512)
fused3d(const float* __restrict__ img, const float* __restrict__ x,
        const float* __restrict__ Wf, const float* __restrict__ bfp,
        float* __restrict__ out)
{
  __shared__ float sImg[TILE_N];
  __shared__ float sX[2][TILE_N];

  const int tid = threadIdx.x;
  const int tx = tid & 7;          // w-pair index 0..7
  const int ty = (tid >> 3) & 7;   // h 0..7
  const int tz = tid >> 6;         // d 0..7 (== wave id)
  const int w0 = blockIdx.x * TX;
  const int h0 = blockIdx.y * TY;
  const int d0 = blockIdx.z * TZ;

  // ---- staging descriptors (same spatial pattern for img and every x batch)
  int  goff[NLOAD];
  bool inb[NLOAD];
#pragma unroll
  for (int k = 0; k < NLOAD; ++k) {
    int i  = tid + k * NT;
    int r  = i / HX;
    int c  = i - r * HX;
    int zz = r / HY;
    int yy = r - zz * HY;
    int gd = d0 + zz - 1;
    int gh = h0 + yy - 1;
    int gw = w0 + c - 1;
    inb[k]  = (i < TILE_N) & ((unsigned)gd < Dm) & ((unsigned)gh < Dm) & ((unsigned)gw < Dm);
    goff[k] = (gd * Dm + gh) * Dm + gw;
  }

  // ---- zero-init LDS tiles: OOB halo slots stay zero forever (loads skip them)
#pragma unroll
  for (int k = 0; k < NLOAD; ++k) {
    int i = tid + k * NT;
    if (i < TILE_N) { sImg[i] = 0.f; sX[0][i] = 0.f; sX[1][i] = 0.f; }
  }
  __syncthreads();

  const int wbase = tid & ~63;   // wave-uniform LDS base (robust to masked lane 0)

  // ---- stage image tile + x batch 0 (async, direct-to-LDS)
#pragma unroll
  for (int k = 0; k < NLOAD; ++k)
    if (inb[k]) gload_lds4(img + goff[k], &sImg[k * NT + wbase]);
#pragma unroll
  for (int k = 0; k < NLOAD; ++k)
    if (inb[k]) gload_lds4(x + goff[k], &sX[0][k * NT + wbase]);
  __syncthreads();

  // ---- per-thread image window: 9 rows x 4 floats (covers both w-pair voxels)
  float iw[9][4];
#pragma unroll
  for (int dz = 0; dz < 3; ++dz)
#pragma unroll
    for (int dy = 0; dy < 3; ++dy) {
      int base = ((tz + dz) * HY + (ty + dy)) * HX + 2 * tx;
      float2 a  = *(const float2*)&sImg[base];
      float2 b2 = *(const float2*)&sImg[base + 2];
      int rr = dz * 3 + dy;
      iw[rr][0] = a.x; iw[rr][1] = a.y; iw[rr][2] = b2.x; iw[rr][3] = b2.y;
    }

  // ---- K[27] per voxel (pair): W,b via uniform scalar loads (s_load), not LDS
  float K0[27], K1[27];
#pragma unroll
  for (int o = 0; o < 27; ++o) {
    float a0 = bfp[o], a1 = bfp[o];
#pragma unroll
    for (int t = 0; t < 27; ++t) {
      float wv = Wf[o * 27 + t];
      int rr = t / 3, cc = t - rr * 3;
      a0 = fmaf(wv, iw[rr][cc],     a0);
      a1 = fmaf(wv, iw[rr][cc + 1], a1);
    }
    K0[o] = a0; K1[o] = a1;
  }

  // ---- batch loop: double-buffered x tiles; prefetch b+1 while computing b
  for (int b = 0; b < Bn; ++b) {
    const int cur = b & 1;
    if (b + 1 < Bn) {
      const float* xb = x + (size_t)(b + 1) * VOX;
#pragma unroll
      for (int k = 0; k < NLOAD; ++k)
        if (inb[k]) gload_lds4(xb + goff[k], &sX[cur ^ 1][k * NT + wbase]);
    }

    const float* sxb = sX[cur];
    float acc0 = 0.f, acc1 = 0.f;
#pragma unroll
    for (int dz = 0; dz < 3; ++dz)
#pragma unroll
      for (int dy = 0; dy < 3; ++dy) {
        int base = ((tz + dz) * HY + (ty + dy)) * HX + 2 * tx;
        float2 a  = *(const float2*)&sxb[base];
        float2 b2 = *(const float2*)&sxb[base + 2];
        int rr = dz * 3 + dy;
        acc0 = fmaf(K0[rr * 3 + 0], a.x,  acc0);
        acc0 = fmaf(K0[rr * 3 + 1], a.y,  acc0);
        acc0 = fmaf(K0[rr * 3 + 2], b2.x, acc0);
        acc1 = fmaf(K1[rr * 3 + 0], a.y,  acc1);
        acc1 = fmaf(K1[rr * 3 + 1], b2.x, acc1);
        acc1 = fmaf(K1[rr * 3 + 2], b2.y, acc1);
      }

    const int od = d0 + tz, oh = h0 + ty, ow = w0 + 2 * tx;
    float2 st; st.x = acc0; st.y = acc1;
    *(float2*)&out[(((size_t)b * Dm + od) * Dm + oh) * Dm + ow] = st;

    __syncthreads();  // drains prefetch (vmcnt0) + guards sX[cur] overwrite next iter
  }
}

extern "C" void kernel_launch(void* const* d_in, const int* in_sizes, int n_in,
                              void* d_out, int out_size, void* d_ws, size_t ws_size,
                              hipStream_t stream) {
  const float* img = (const float*)d_in[0];
  const float* x   = (const float*)d_in[1];
  const float* Wf  = (const float*)d_in[2];
  const float* bf  = (const float*)d_in[3];
  float* out = (float*)d_out;
  dim3 grid(Dm / TX, Dm / TY, Dm / TZ);  // 8 x 16 x 16 = 2048 blocks
  hipLaunchKernelGGL(fused3d, grid, dim3(NT), 0, stream, img, x, Wf, bf, out);
}